// Round 8
// baseline (145.653 us; speedup 1.0000x reference)
//
#include <hip/hip_runtime.h>

#define BLANK 36
#define NEG -1e30f
#define CC 37
#define LOG32 3.4657359027997265f

__device__ __forceinline__ float logaddexp_f(float a, float b) {
    float m = fmaxf(a, b);
    float d = fabsf(a - b);
    return m + __logf(1.0f + __expf(-d));
}

// ============ FAST PATH: fused, linear-domain recurrence ===================
// One wave per sample; T chunked by 64. LDS double buffer holds 32*softmax
// probabilities (raw logits staged, overwritten in place by row softmax).
// Recurrence in linear domain: z'[s] = (z[s]+z[s-1]+z[s-2]*skip) * (32*p),
// masked to 0 on invalid lanes (required: 32*p can exceed 1 -> growth).
// The x32 fold makes z near-stationary (typ 32/37 per step); butterfly-max
// rescale every 8 steps bounds drift; capture converts to log domain with a
// clamp (no zero cliff -> no NEG blowup, the R7 failure).
// LDS: 4 waves * 2*2368 floats = 75776 B -> 2 blocks/CU.
__global__ __launch_bounds__(256) void ctc_fused_lin_kernel(
    const float* __restrict__ logits,        // [B, T, C]
    const int*   __restrict__ targets,       // [B * L]
    const int*   __restrict__ input_lengths, // [B]
    const int*   __restrict__ target_lengths,// [B]
    float*       __restrict__ per_sample,    // [B]
    int B, int T, int L)
{
    __shared__ float lds[4 * 4736];
    const int lane = threadIdx.x & 63;
    const int wib  = threadIdx.x >> 6;
    const int b    = blockIdx.x * 4 + wib;
    if (b >= B) return;

    float* X0 = lds + wib * 4736;     // 2368 floats (chunk probs, dbuf A)
    float* X1 = X0 + 2368;            // dbuf B

    const int S = 2 * L + 1;
    // force wave-uniform values into SGPRs -> capture/final branches are scalar
    const int tlen_s = __builtin_amdgcn_readfirstlane(target_lengths[b]);
    const int ilen_s = __builtin_amdgcn_readfirstlane(input_lengths[b]);
    const int end_s  = 2 * tlen_s;

    int ext_s = BLANK;                // < CC always -> LDS reads in-bounds
    if (lane < S && (lane & 1)) ext_s = targets[b * L + (lane >> 1)];
    const int ext_sm2 = __shfl_up(ext_s, 2);
    const bool skip_ok = (lane < S) && (lane >= 2) && (ext_s != BLANK) && (ext_s != ext_sm2);
    const bool valid = lane < (2 * tlen_s + 1);

    const float4* src = (const float4*)(logits + (size_t)b * T * CC);  // 16B-aligned

    float z    = 0.0f;                // z[s] ~ exp(alpha[s] + (t+1)*log32 - racc)
    float racc = 0.0f;                // accumulated rescale logs
    float capv = NEG;                 // captured log-alpha at t+1 == ilen

    auto ZSTEP = [&](float p, int tt) {
        float z1 = __shfl_up(z, 1);
        z1 = (lane == 0) ? 0.0f : z1;
        float z2 = __shfl_up(z, 2);
        z2 = skip_ok ? z2 : 0.0f;
        const float zn = (z + z1 + z2) * p;
        z = valid ? zn : 0.0f;        // mask: invalid lanes must stay 0
        if (ilen_s == tt + 1) {       // scalar (wave-uniform) branch, taken once
            capv = __logf(fmaxf(z, 1e-35f)) + racc - (float)(tt + 1) * LOG32;
        }
    };

    auto RESCALE = [&]() {
        float m = z;
        #pragma unroll
        for (int o = 32; o > 0; o >>= 1) m = fmaxf(m, __shfl_xor(m, o));
        m = fmaxf(m, 1e-30f);         // guard all-zero
        z *= (1.0f / m);
        racc += __logf(m);            // off the z chain
    };

    // In-place row softmax scaled by 32: lane owns row `lane` exclusively.
    auto SOFTMAX = [&](float* Xn) {
        float xr[CC];
        const float* row = Xn + lane * CC;
        #pragma unroll
        for (int c2 = 0; c2 < CC; ++c2) xr[c2] = row[c2];
        float m = xr[0];
        #pragma unroll
        for (int c2 = 1; c2 < CC; ++c2) m = fmaxf(m, xr[c2]);
        float ss = 0.0f;
        #pragma unroll
        for (int c2 = 0; c2 < CC; ++c2) { xr[c2] = __expf(xr[c2] - m); ss += xr[c2]; }
        const float inv = 32.0f / ss;           // x32 fold
        float* wrow = Xn + lane * CC;
        #pragma unroll
        for (int c2 = 0; c2 < CC; ++c2) wrow[c2] = xr[c2] * inv;
    };

    // ---- prologue: stage + softmax chunk 0 ----
    {
        float4* dst = (float4*)X0;
        #pragma unroll
        for (int k = 0; k < 9; ++k) dst[k * 64 + lane] = src[k * 64 + lane];
        if (lane < 16) dst[576 + lane] = src[576 + lane];   // 592 = 9*64+16
        __builtin_amdgcn_s_waitcnt(0);
        SOFTMAX(X0);
        __builtin_amdgcn_s_waitcnt(0);
    }

    const int NC = T >> 6;            // chunks of 64 (T % 64 == 0 on this path)
    for (int c = 0; c < NC; ++c) {
        float* Xb = (c & 1) ? X1 : X0;
        const bool more = (c + 1 < NC);

        // (a) issue global loads for chunk c+1 (named regs; hidden by (b))
        float4 f0 = {}, f1 = {}, f2 = {}, f3 = {}, f4 = {},
               f5 = {}, f6 = {}, f7 = {}, f8 = {}, f9 = {};
        if (more) {
            const float4* s2 = src + (size_t)(c + 1) * 592;
            f0 = s2[lane];       f1 = s2[64 + lane];  f2 = s2[128 + lane];
            f3 = s2[192 + lane]; f4 = s2[256 + lane]; f5 = s2[320 + lane];
            f6 = s2[384 + lane]; f7 = s2[448 + lane]; f8 = s2[512 + lane];
            if (lane < 16) f9 = s2[576 + lane];
        }

        // (b) 64 steps; probs read with 4-step named-register lookahead
        const int tbase = c << 6;
        float p0 = Xb[0 * CC + ext_s];
        float p1 = Xb[1 * CC + ext_s];
        float p2 = Xb[2 * CC + ext_s];
        float p3 = Xb[3 * CC + ext_s];
        float q0, q1, q2, q3;
        int g = 0;
        if (c == 0) {                 // t = 0 init peeled
            z = (valid && lane <= 1) ? p0 : 0.0f;
            if (ilen_s == 1) capv = __logf(fmaxf(z, 1e-35f)) - LOG32;
            q0 = Xb[4 * CC + ext_s];
            q1 = Xb[5 * CC + ext_s];
            q2 = Xb[6 * CC + ext_s];
            q3 = Xb[7 * CC + ext_s];
            ZSTEP(p1, 1); ZSTEP(p2, 2); ZSTEP(p3, 3);
            p0 = q0; p1 = q1; p2 = q2; p3 = q3;
            g = 1;
        }
        for (; g < 16; ++g) {
            const int r = (g + 1) << 2;
            if (g < 15) {
                q0 = Xb[(r + 0) * CC + ext_s];
                q1 = Xb[(r + 1) * CC + ext_s];
                q2 = Xb[(r + 2) * CC + ext_s];
                q3 = Xb[(r + 3) * CC + ext_s];
            }
            const int tt = tbase + (g << 2);
            ZSTEP(p0, tt); ZSTEP(p1, tt + 1); ZSTEP(p2, tt + 2); ZSTEP(p3, tt + 3);
            p0 = q0; p1 = q1; p2 = q2; p3 = q3;
            if (g & 1) RESCALE();     // every 8 steps
        }

        // (c) commit staged chunk c+1, softmax rows in place
        if (more) {
            float* Xn = (c & 1) ? X0 : X1;
            float4* dst = (float4*)Xn;
            dst[lane] = f0;       dst[64 + lane] = f1;  dst[128 + lane] = f2;
            dst[192 + lane] = f3; dst[256 + lane] = f4; dst[320 + lane] = f5;
            dst[384 + lane] = f6; dst[448 + lane] = f7; dst[512 + lane] = f8;
            if (lane < 16) dst[576 + lane] = f9;
            __builtin_amdgcn_s_waitcnt(0);
            SOFTMAX(Xn);
            __builtin_amdgcn_s_waitcnt(0);
        }
    }

    // ---- final_ll once ----
    const float e1 = __shfl(capv, end_s);
    const float e2 = __shfl(capv, end_s - 1);
    const float final_v = logaddexp_f(e1, e2);
    if (lane == 0) per_sample[b] = -final_v / (float)tlen_s;
}

// ============ FALLBACK PATH (proven R2 kernels) ============================
__global__ __launch_bounds__(256) void lse_kernel(
    const float* __restrict__ logits, float* __restrict__ denom, int N)
{
    __shared__ float lds[256 * CC];
    const int lane = threadIdx.x & 63;
    const int wib  = threadIdx.x >> 6;
    const int wave = blockIdx.x * 4 + wib;
    const long long row0 = (long long)wave * 64;
    if (row0 >= N) return;
    const int wbase = wib * 64 * CC;
    const float4* src4 = (const float4*)(logits + row0 * CC);
    const long long n4_remaining = ((long long)N * CC - row0 * CC) / 4;
    float4* lds4 = (float4*)(lds + wbase);
    #pragma unroll
    for (int k = 0; k < 10; ++k) {
        const int idx = k * 64 + lane;
        if (idx < 592 && idx < n4_remaining) lds4[idx] = src4[idx];
    }
    __builtin_amdgcn_s_waitcnt(0);
    const long long row = row0 + lane;
    if (row >= N) return;
    const float* x = lds + wbase + lane * CC;
    float m = x[0];
    #pragma unroll
    for (int c = 1; c < CC; ++c) m = fmaxf(m, x[c]);
    float s = 0.0f;
    #pragma unroll
    for (int c = 0; c < CC; ++c) s += __expf(x[c] - m);
    denom[row] = m + __logf(s);
}

__global__ __launch_bounds__(256) void ctc_alpha2_kernel(
    const float* __restrict__ logits, const float* __restrict__ denom,
    const int* __restrict__ targets, const int* __restrict__ input_lengths,
    const int* __restrict__ target_lengths, float* __restrict__ per_sample,
    int B, int T, int L)
{
    const int wave = (int)((blockIdx.x * blockDim.x + threadIdx.x) >> 6);
    const int lane = threadIdx.x & 63;
    if (wave >= B) return;
    const int b = wave;
    const int S = 2 * L + 1;
    const int tlen = target_lengths[b];
    const int ilen = input_lengths[b];
    const int end_idx = 2 * tlen;
    int ext_s = BLANK;
    if (lane < S && (lane & 1)) ext_s = targets[b * L + (lane >> 1)];
    const int ext_sm2 = __shfl_up(ext_s, 2);
    const bool skip_ok = (lane < S) && (lane >= 2) && (ext_s != BLANK) && (ext_s != ext_sm2);
    const bool valid = lane < (2 * tlen + 1);
    const float* lg = logits + (size_t)b * T * CC;
    const float* dn = denom + (size_t)b * T;
    float x_cur = lg[ext_s];
    float d_cur = dn[0];
    float x_nx = (T > 1) ? lg[CC + ext_s] : 0.0f;
    float d_nx = (T > 1) ? dn[1] : 0.0f;
    float final_v = NEG;
    float alpha = (valid && lane <= 1) ? (x_cur - d_cur) : NEG;
    if (ilen == 1) {
        const float e1 = __shfl(alpha, end_idx);
        const float e2 = __shfl(alpha, end_idx - 1);
        final_v = logaddexp_f(e1, e2);
    }
    for (int tt = 1; tt < T; ++tt) {
        x_cur = x_nx; d_cur = d_nx;
        if (tt + 1 < T) {
            x_nx = lg[(size_t)(tt + 1) * CC + ext_s];
            d_nx = dn[tt + 1];
        }
        const float lpe = x_cur - d_cur;
        float a1 = __shfl_up(alpha, 1);
        if (lane == 0) a1 = NEG;
        float a2 = __shfl_up(alpha, 2);
        if (!skip_ok) a2 = NEG;
        const float m = fmaxf(fmaxf(alpha, a1), a2);
        const float s = __expf(alpha - m) + __expf(a1 - m) + __expf(a2 - m);
        const float na = m + __logf(s) + lpe;
        alpha = valid ? na : NEG;
        if (ilen == tt + 1) {
            const float e1 = __shfl(alpha, end_idx);
            const float e2 = __shfl(alpha, end_idx - 1);
            final_v = logaddexp_f(e1, e2);
        }
    }
    if (lane == 0) per_sample[b] = -final_v / (float)tlen;
}

__global__ __launch_bounds__(256) void ctc_alpha_mono_kernel(
    const float* __restrict__ logits, const int* __restrict__ targets,
    const int* __restrict__ input_lengths, const int* __restrict__ target_lengths,
    float* __restrict__ per_sample, int B, int T, int L)
{
    const int wave = (int)((blockIdx.x * blockDim.x + threadIdx.x) >> 6);
    const int lane = threadIdx.x & 63;
    if (wave >= B) return;
    const int b = wave;
    const int S = 2 * L + 1;
    const int tlen = target_lengths[b];
    const int ilen = input_lengths[b];
    const int end_idx = 2 * tlen;
    int ext_s = BLANK;
    if (lane < S && (lane & 1)) ext_s = targets[b * L + (lane >> 1)];
    const int ext_sm2 = __shfl_up(ext_s, 2);
    const bool skip_ok = (lane < S) && (lane >= 2) && (ext_s != BLANK) && (ext_s != ext_sm2);
    const bool valid = lane < (2 * tlen + 1);
    const float* lg = logits + (size_t)b * T * CC;
    float alpha = NEG, final_v = NEG;
    for (int t = 0; t < T; ++t) {
        float x = (lane < CC) ? lg[t * CC + lane] : -3.0e38f;
        float mx = x;
        #pragma unroll
        for (int o = 32; o > 0; o >>= 1) mx = fmaxf(mx, __shfl_xor(mx, o));
        float e = (lane < CC) ? __expf(x - mx) : 0.0f;
        float se = e;
        #pragma unroll
        for (int o = 32; o > 0; o >>= 1) se += __shfl_xor(se, o);
        const float lp = x - mx - __logf(se);
        const float lpe = __shfl(lp, ext_s);
        float newa;
        if (t == 0) {
            newa = (lane <= 1) ? lpe : NEG;
        } else {
            float a1 = __shfl_up(alpha, 1);
            if (lane == 0) a1 = NEG;
            float a2 = __shfl_up(alpha, 2);
            if (!skip_ok) a2 = NEG;
            newa = logaddexp_f(logaddexp_f(alpha, a1), a2) + lpe;
        }
        if (!valid) newa = NEG;
        alpha = newa;
        if (ilen == t + 1) {
            const float e1 = __shfl(alpha, end_idx);
            const float e2 = __shfl(alpha, end_idx - 1);
            final_v = logaddexp_f(e1, e2);
        }
    }
    if (lane == 0) per_sample[b] = -final_v / (float)tlen;
}

// ---------------- Deterministic mean over B samples ------------------------
__global__ __launch_bounds__(256) void reduce_mean_kernel(
    const float* __restrict__ ps, float* __restrict__ out, int B)
{
    float s = 0.0f;
    for (int i = threadIdx.x; i < B; i += 256) s += ps[i];
    #pragma unroll
    for (int o = 32; o > 0; o >>= 1) s += __shfl_xor(s, o);
    __shared__ float sm[4];
    const int w = threadIdx.x >> 6, l = threadIdx.x & 63;
    if (l == 0) sm[w] = s;
    __syncthreads();
    if (threadIdx.x == 0) {
        out[0] = (sm[0] + sm[1] + sm[2] + sm[3]) / (float)B;
    }
}

extern "C" void kernel_launch(void* const* d_in, const int* in_sizes, int n_in,
                              void* d_out, int out_size, void* d_ws, size_t ws_size,
                              hipStream_t stream) {
    const float* logits         = (const float*)d_in[0];
    const int*   targets        = (const int*)d_in[1];
    const int*   input_lengths  = (const int*)d_in[2];
    const int*   target_lengths = (const int*)d_in[3];

    const int B = in_sizes[2];
    const int L = in_sizes[1] / B;
    const int T = in_sizes[0] / (B * CC);
    const long long N = (long long)B * T;

    float* per_sample = (float*)d_ws;               // B floats
    float* scratch    = per_sample + B;             // denom (fallback only)
    float* out        = (float*)d_out;

    const size_t ws_mid = ((size_t)B + (size_t)N) * sizeof(float);
    const int nblocks_alpha = (B * 64 + 255) / 256;
    const long long nwaves = (N + 63) / 64;

    if ((T % 64 == 0) && T >= 64 && L <= 31 && ws_size >= (size_t)B * sizeof(float)) {
        ctc_fused_lin_kernel<<<(B + 3) / 4, 256, 0, stream>>>(
            logits, targets, input_lengths, target_lengths, per_sample, B, T, L);
    } else if (ws_size >= ws_mid && T >= 2) {
        lse_kernel<<<(int)((nwaves + 3) / 4), 256, 0, stream>>>(logits, scratch, (int)N);
        ctc_alpha2_kernel<<<nblocks_alpha, 256, 0, stream>>>(
            logits, scratch, targets, input_lengths, target_lengths, per_sample, B, T, L);
    } else {
        ctc_alpha_mono_kernel<<<nblocks_alpha, 256, 0, stream>>>(
            logits, targets, input_lengths, target_lengths, per_sample, B, T, L);
    }
    reduce_mean_kernel<<<1, 256, 0, stream>>>(per_sample, out, B);
}

// Round 9
// 135.873 us; speedup vs baseline: 1.0720x; 1.0720x over previous
//
#include <hip/hip_runtime.h>

#define BLANK 36
#define NEG -1e30f
#define CC 37
#define LOG37 3.6109179126442243f

__device__ __forceinline__ float logaddexp_f(float a, float b) {
    float m = fmaxf(a, b);
    float d = fabsf(a - b);
    return m + __logf(1.0f + __expf(-d));
}

// ============ FAST PATH: fused, linear domain, 2-step composed =============
// One wave per sample; T chunked by 64. LDS double buffer holds 37*softmax
// probabilities. Two time-steps are composed into ONE shuffle round:
//   alpha_{t+2}[s] = Q[s]*( P[s]*G0 + 1_{s>=1}P[s-1]*G1 + k[s]P[s-2]*G2 )
//   G0 = a + a1 + k*a2 ; G1 = a1 + a2 + k1*a3 ; G2 = a2 + a3 + k2*a4
// (a1..a4 = shfl_up(z,1..4), all PARALLEL -> one bpermute latency per 2 steps
//  instead of two serial rounds: the R8 bottleneck). P-gathers are off-chain,
// prefetched one group ahead. Rescale butterfly every 16 steps (half of R8).
// x37 fold keeps z near-stationary; capture clamps (no zero cliff).
__global__ __launch_bounds__(256) void ctc_fused_lin2_kernel(
    const float* __restrict__ logits,        // [B, T, C]
    const int*   __restrict__ targets,       // [B * L]
    const int*   __restrict__ input_lengths, // [B]
    const int*   __restrict__ target_lengths,// [B]
    float*       __restrict__ per_sample,    // [B]
    int B, int T, int L)
{
    __shared__ float lds[4 * 4736];
    const int lane = threadIdx.x & 63;
    const int wib  = threadIdx.x >> 6;
    const int b    = blockIdx.x * 4 + wib;
    if (b >= B) return;

    float* X0 = lds + wib * 4736;
    float* X1 = X0 + 2368;

    const int S = 2 * L + 1;
    const int tlen_s = __builtin_amdgcn_readfirstlane(target_lengths[b]);
    const int ilen_s = __builtin_amdgcn_readfirstlane(input_lengths[b]);
    const int end_s  = 2 * tlen_s;

    int ext_s = BLANK;                 // < CC always -> LDS gathers in-bounds
    if (lane < S && (lane & 1)) ext_s = targets[b * L + (lane >> 1)];
    const int es1 = __shfl_up(ext_s, 1);   // garbage at lane 0 (masked below)
    const int es2 = __shfl_up(ext_s, 2);   // garbage at lanes <2 (kf=0 there)
    const bool skip_ok = (lane < S) && (lane >= 2) && (ext_s != BLANK) && (ext_s != es2);
    const float kf  = skip_ok ? 1.0f : 0.0f;
    float k1t = __shfl_up(kf, 1);          // k[s-1]; multiplies a3 (0 for lane<3)
    float k2t = __shfl_up(kf, 2);          // k[s-2]; multiplies a4 (0 for lane<4)
    const float k1f = k1t, k2f = k2t;
    const float m1f = (lane >= 1) ? 1.0f : 0.0f;
    const bool  valid  = lane < (2 * tlen_s + 1);
    const float validm = valid ? 1.0f : 0.0f;

    const float4* src = (const float4*)(logits + (size_t)b * T * CC);

    float z = 0.0f, racc = 0.0f, capv = NEG;

    auto PAIR = [&](float Ps, float Pm1, float Pm2, float Qv, int tt) {
        float a1 = __shfl_up(z, 1); a1 = (lane >= 1) ? a1 : 0.0f;
        float a2 = __shfl_up(z, 2); a2 = (lane >= 2) ? a2 : 0.0f;
        float a3 = __shfl_up(z, 3); a3 = (lane >= 3) ? a3 : 0.0f;
        float a4 = __shfl_up(z, 4); a4 = (lane >= 4) ? a4 : 0.0f;
        const float G0 = fmaf(kf,  a2, z  + a1);
        const float G1 = fmaf(k1f, a3, a1 + a2);
        const float G2 = fmaf(k2f, a4, a2 + a3);
        const float A1v = Ps * G0;                  // alpha at tt+1 (byproduct)
        if (ilen_s == tt + 1)
            capv = __logf(fmaxf(A1v, 1e-35f)) + racc - (float)(tt + 1) * LOG37;
        float r = fmaf(Pm1, G1, A1v);
        r = fmaf(Pm2, G2, r);
        z = Qv * r;                                 // Qv includes validm
        if (ilen_s == tt + 2)
            capv = __logf(fmaxf(z, 1e-35f)) + racc - (float)(tt + 2) * LOG37;
    };

    auto ZSTEP1 = [&](float Qv, int tt) {           // single plain step
        float a1 = __shfl_up(z, 1); a1 = (lane >= 1) ? a1 : 0.0f;
        float a2 = __shfl_up(z, 2); a2 = (lane >= 2) ? a2 : 0.0f;
        z = fmaf(kf, a2, z + a1) * Qv;
        if (ilen_s == tt + 1)
            capv = __logf(fmaxf(z, 1e-35f)) + racc - (float)(tt + 1) * LOG37;
    };

    auto RESCALE = [&]() {
        float m = z;
        #pragma unroll
        for (int o = 32; o > 0; o >>= 1) m = fmaxf(m, __shfl_xor(m, o));
        m = fmaxf(m, 1e-30f);
        z *= (1.0f / m);
        racc += __logf(m);
    };

    auto SOFTMAX = [&](float* Xn) {    // in-place row softmax scaled by 37
        float xr[CC];
        const float* row = Xn + lane * CC;
        #pragma unroll
        for (int c2 = 0; c2 < CC; ++c2) xr[c2] = row[c2];
        float m = xr[0];
        #pragma unroll
        for (int c2 = 1; c2 < CC; ++c2) m = fmaxf(m, xr[c2]);
        float ss = 0.0f;
        #pragma unroll
        for (int c2 = 0; c2 < CC; ++c2) { xr[c2] = __expf(xr[c2] - m); ss += xr[c2]; }
        const float inv = 37.0f / ss;
        float* wrow = Xn + lane * CC;
        #pragma unroll
        for (int c2 = 0; c2 < CC; ++c2) wrow[c2] = xr[c2] * inv;
    };

    // ---- prologue: stage + softmax chunk 0 ----
    {
        float4* dst = (float4*)X0;
        #pragma unroll
        for (int k = 0; k < 9; ++k) dst[k * 64 + lane] = src[k * 64 + lane];
        if (lane < 16) dst[576 + lane] = src[576 + lane];
        __builtin_amdgcn_s_waitcnt(0);
        SOFTMAX(X0);
        __builtin_amdgcn_s_waitcnt(0);
    }

    const int NC = T >> 6;
    for (int c = 0; c < NC; ++c) {
        float* Xb = (c & 1) ? X1 : X0;
        const bool more = (c + 1 < NC);

        // (a) issue global loads for chunk c+1
        float4 f0 = {}, f1 = {}, f2 = {}, f3 = {}, f4 = {},
               f5 = {}, f6 = {}, f7 = {}, f8 = {}, f9 = {};
        if (more) {
            const float4* s2 = src + (size_t)(c + 1) * 592;
            f0 = s2[lane];       f1 = s2[64 + lane];  f2 = s2[128 + lane];
            f3 = s2[192 + lane]; f4 = s2[256 + lane]; f5 = s2[320 + lane];
            f6 = s2[384 + lane]; f7 = s2[448 + lane]; f8 = s2[512 + lane];
            if (lane < 16) f9 = s2[576 + lane];
        }

        // (b) recurrence on chunk c
        const int tbase = c << 6;
        float Ps, Pm1, Pm2, Qv, nPs, nPm1, nPm2, nQv;
        if (c == 0) {
            // t=0 init + single step t=1, then 31 pairs on rows 2..63
            const float P0 = Xb[ext_s];
            const float Q1 = Xb[CC + ext_s] * validm;
            z = ((lane <= 1) ? P0 : 0.0f) * validm;
            if (ilen_s == 1)
                capv = __logf(fmaxf(z, 1e-35f)) - LOG37;
            ZSTEP1(Q1, 1);
            // pre-gather rows 2,3
            Ps  = Xb[2 * CC + ext_s];
            Pm1 = m1f * Xb[2 * CC + es1];
            Pm2 = kf  * Xb[2 * CC + es2];
            Qv  = Xb[3 * CC + ext_s] * validm;
            #pragma unroll
            for (int g = 0; g < 31; ++g) {
                if (g < 30) {
                    const int r = 4 + 2 * g;
                    nPs  = Xb[r * CC + ext_s];
                    nPm1 = m1f * Xb[r * CC + es1];
                    nPm2 = kf  * Xb[r * CC + es2];
                    nQv  = Xb[(r + 1) * CC + ext_s] * validm;
                }
                PAIR(Ps, Pm1, Pm2, Qv, 2 + 2 * g);
                Ps = nPs; Pm1 = nPm1; Pm2 = nPm2; Qv = nQv;
                if ((g & 7) == 7 || g == 30) RESCALE();
            }
        } else {
            // 32 pairs on rows 0..63
            Ps  = Xb[ext_s];
            Pm1 = m1f * Xb[es1];
            Pm2 = kf  * Xb[es2];
            Qv  = Xb[CC + ext_s] * validm;
            #pragma unroll
            for (int g = 0; g < 32; ++g) {
                if (g < 31) {
                    const int r = 2 + 2 * g;
                    nPs  = Xb[r * CC + ext_s];
                    nPm1 = m1f * Xb[r * CC + es1];
                    nPm2 = kf  * Xb[r * CC + es2];
                    nQv  = Xb[(r + 1) * CC + ext_s] * validm;
                }
                PAIR(Ps, Pm1, Pm2, Qv, tbase + 2 * g);
                Ps = nPs; Pm1 = nPm1; Pm2 = nPm2; Qv = nQv;
                if ((g & 7) == 7) RESCALE();
            }
        }

        // (c) commit staged chunk c+1, softmax rows in place
        if (more) {
            float* Xn = (c & 1) ? X0 : X1;
            float4* dst = (float4*)Xn;
            dst[lane] = f0;       dst[64 + lane] = f1;  dst[128 + lane] = f2;
            dst[192 + lane] = f3; dst[256 + lane] = f4; dst[320 + lane] = f5;
            dst[384 + lane] = f6; dst[448 + lane] = f7; dst[512 + lane] = f8;
            if (lane < 16) dst[576 + lane] = f9;
            __builtin_amdgcn_s_waitcnt(0);
            SOFTMAX(Xn);
            __builtin_amdgcn_s_waitcnt(0);
        }
    }

    // ---- final_ll once ----
    const float e1 = __shfl(capv, end_s);
    const float e2 = __shfl(capv, end_s - 1);
    const float final_v = logaddexp_f(e1, e2);
    if (lane == 0) per_sample[b] = -final_v / (float)tlen_s;
}

// ============ FALLBACK PATH (proven R2 kernels) ============================
__global__ __launch_bounds__(256) void lse_kernel(
    const float* __restrict__ logits, float* __restrict__ denom, int N)
{
    __shared__ float lds[256 * CC];
    const int lane = threadIdx.x & 63;
    const int wib  = threadIdx.x >> 6;
    const int wave = blockIdx.x * 4 + wib;
    const long long row0 = (long long)wave * 64;
    if (row0 >= N) return;
    const int wbase = wib * 64 * CC;
    const float4* src4 = (const float4*)(logits + row0 * CC);
    const long long n4_remaining = ((long long)N * CC - row0 * CC) / 4;
    float4* lds4 = (float4*)(lds + wbase);
    #pragma unroll
    for (int k = 0; k < 10; ++k) {
        const int idx = k * 64 + lane;
        if (idx < 592 && idx < n4_remaining) lds4[idx] = src4[idx];
    }
    __builtin_amdgcn_s_waitcnt(0);
    const long long row = row0 + lane;
    if (row >= N) return;
    const float* x = lds + wbase + lane * CC;
    float m = x[0];
    #pragma unroll
    for (int c = 1; c < CC; ++c) m = fmaxf(m, x[c]);
    float s = 0.0f;
    #pragma unroll
    for (int c = 0; c < CC; ++c) s += __expf(x[c] - m);
    denom[row] = m + __logf(s);
}

__global__ __launch_bounds__(256) void ctc_alpha2_kernel(
    const float* __restrict__ logits, const float* __restrict__ denom,
    const int* __restrict__ targets, const int* __restrict__ input_lengths,
    const int* __restrict__ target_lengths, float* __restrict__ per_sample,
    int B, int T, int L)
{
    const int wave = (int)((blockIdx.x * blockDim.x + threadIdx.x) >> 6);
    const int lane = threadIdx.x & 63;
    if (wave >= B) return;
    const int b = wave;
    const int S = 2 * L + 1;
    const int tlen = target_lengths[b];
    const int ilen = input_lengths[b];
    const int end_idx = 2 * tlen;
    int ext_s = BLANK;
    if (lane < S && (lane & 1)) ext_s = targets[b * L + (lane >> 1)];
    const int ext_sm2 = __shfl_up(ext_s, 2);
    const bool skip_ok = (lane < S) && (lane >= 2) && (ext_s != BLANK) && (ext_s != ext_sm2);
    const bool valid = lane < (2 * tlen + 1);
    const float* lg = logits + (size_t)b * T * CC;
    const float* dn = denom + (size_t)b * T;
    float x_cur = lg[ext_s];
    float d_cur = dn[0];
    float x_nx = (T > 1) ? lg[CC + ext_s] : 0.0f;
    float d_nx = (T > 1) ? dn[1] : 0.0f;
    float final_v = NEG;
    float alpha = (valid && lane <= 1) ? (x_cur - d_cur) : NEG;
    if (ilen == 1) {
        const float e1 = __shfl(alpha, end_idx);
        const float e2 = __shfl(alpha, end_idx - 1);
        final_v = logaddexp_f(e1, e2);
    }
    for (int tt = 1; tt < T; ++tt) {
        x_cur = x_nx; d_cur = d_nx;
        if (tt + 1 < T) {
            x_nx = lg[(size_t)(tt + 1) * CC + ext_s];
            d_nx = dn[tt + 1];
        }
        const float lpe = x_cur - d_cur;
        float a1 = __shfl_up(alpha, 1);
        if (lane == 0) a1 = NEG;
        float a2 = __shfl_up(alpha, 2);
        if (!skip_ok) a2 = NEG;
        const float m = fmaxf(fmaxf(alpha, a1), a2);
        const float s = __expf(alpha - m) + __expf(a1 - m) + __expf(a2 - m);
        const float na = m + __logf(s) + lpe;
        alpha = valid ? na : NEG;
        if (ilen == tt + 1) {
            const float e1 = __shfl(alpha, end_idx);
            const float e2 = __shfl(alpha, end_idx - 1);
            final_v = logaddexp_f(e1, e2);
        }
    }
    if (lane == 0) per_sample[b] = -final_v / (float)tlen;
}

__global__ __launch_bounds__(256) void ctc_alpha_mono_kernel(
    const float* __restrict__ logits, const int* __restrict__ targets,
    const int* __restrict__ input_lengths, const int* __restrict__ target_lengths,
    float* __restrict__ per_sample, int B, int T, int L)
{
    const int wave = (int)((blockIdx.x * blockDim.x + threadIdx.x) >> 6);
    const int lane = threadIdx.x & 63;
    if (wave >= B) return;
    const int b = wave;
    const int S = 2 * L + 1;
    const int tlen = target_lengths[b];
    const int ilen = input_lengths[b];
    const int end_idx = 2 * tlen;
    int ext_s = BLANK;
    if (lane < S && (lane & 1)) ext_s = targets[b * L + (lane >> 1)];
    const int ext_sm2 = __shfl_up(ext_s, 2);
    const bool skip_ok = (lane < S) && (lane >= 2) && (ext_s != BLANK) && (ext_s != ext_sm2);
    const bool valid = lane < (2 * tlen + 1);
    const float* lg = logits + (size_t)b * T * CC;
    float alpha = NEG, final_v = NEG;
    for (int t = 0; t < T; ++t) {
        float x = (lane < CC) ? lg[t * CC + lane] : -3.0e38f;
        float mx = x;
        #pragma unroll
        for (int o = 32; o > 0; o >>= 1) mx = fmaxf(mx, __shfl_xor(mx, o));
        float e = (lane < CC) ? __expf(x - mx) : 0.0f;
        float se = e;
        #pragma unroll
        for (int o = 32; o > 0; o >>= 1) se += __shfl_xor(se, o);
        const float lp = x - mx - __logf(se);
        const float lpe = __shfl(lp, ext_s);
        float newa;
        if (t == 0) {
            newa = (lane <= 1) ? lpe : NEG;
        } else {
            float a1 = __shfl_up(alpha, 1);
            if (lane == 0) a1 = NEG;
            float a2 = __shfl_up(alpha, 2);
            if (!skip_ok) a2 = NEG;
            newa = logaddexp_f(logaddexp_f(alpha, a1), a2) + lpe;
        }
        if (!valid) newa = NEG;
        alpha = newa;
        if (ilen == t + 1) {
            const float e1 = __shfl(alpha, end_idx);
            const float e2 = __shfl(alpha, end_idx - 1);
            final_v = logaddexp_f(e1, e2);
        }
    }
    if (lane == 0) per_sample[b] = -final_v / (float)tlen;
}

// ---------------- Deterministic mean over B samples ------------------------
__global__ __launch_bounds__(256) void reduce_mean_kernel(
    const float* __restrict__ ps, float* __restrict__ out, int B)
{
    float s = 0.0f;
    for (int i = threadIdx.x; i < B; i += 256) s += ps[i];
    #pragma unroll
    for (int o = 32; o > 0; o >>= 1) s += __shfl_xor(s, o);
    __shared__ float sm[4];
    const int w = threadIdx.x >> 6, l = threadIdx.x & 63;
    if (l == 0) sm[w] = s;
    __syncthreads();
    if (threadIdx.x == 0) {
        out[0] = (sm[0] + sm[1] + sm[2] + sm[3]) / (float)B;
    }
}

extern "C" void kernel_launch(void* const* d_in, const int* in_sizes, int n_in,
                              void* d_out, int out_size, void* d_ws, size_t ws_size,
                              hipStream_t stream) {
    const float* logits         = (const float*)d_in[0];
    const int*   targets        = (const int*)d_in[1];
    const int*   input_lengths  = (const int*)d_in[2];
    const int*   target_lengths = (const int*)d_in[3];

    const int B = in_sizes[2];
    const int L = in_sizes[1] / B;
    const int T = in_sizes[0] / (B * CC);
    const long long N = (long long)B * T;

    float* per_sample = (float*)d_ws;
    float* scratch    = per_sample + B;
    float* out        = (float*)d_out;

    const size_t ws_mid = ((size_t)B + (size_t)N) * sizeof(float);
    const int nblocks_alpha = (B * 64 + 255) / 256;
    const long long nwaves = (N + 63) / 64;

    if ((T % 64 == 0) && T >= 64 && L <= 31 && ws_size >= (size_t)B * sizeof(float)) {
        ctc_fused_lin2_kernel<<<(B + 3) / 4, 256, 0, stream>>>(
            logits, targets, input_lengths, target_lengths, per_sample, B, T, L);
    } else if (ws_size >= ws_mid && T >= 2) {
        lse_kernel<<<(int)((nwaves + 3) / 4), 256, 0, stream>>>(logits, scratch, (int)N);
        ctc_alpha2_kernel<<<nblocks_alpha, 256, 0, stream>>>(
            logits, scratch, targets, input_lengths, target_lengths, per_sample, B, T, L);
    } else {
        ctc_alpha_mono_kernel<<<nblocks_alpha, 256, 0, stream>>>(
            logits, targets, input_lengths, target_lengths, per_sample, B, T, L);
    }
    reduce_mean_kernel<<<1, 256, 0, stream>>>(per_sample, out, B);
}